// Round 5
// baseline (408.932 us; speedup 1.0000x reference)
//
#include <hip/hip_runtime.h>
#include <cstdint>

// Problem sizes (fixed by reference)
#define S_    2048
#define DM    1024
#define DH    4096
#define NTOK  8192     // B*S = 4*2048
#define WELEM 4194304  // 4096*1024 elements in each weight matrix
#define CT    8        // tokens per conv block

typedef int v4i __attribute__((ext_vector_type(4)));

// ---------------------------------------------------------------------------
// Per-block partial sums of |w| in fp64, both matrices in one launch.
// Blocks [0,1024) -> w1, [1024,2048) -> w2. Deterministic fixed mapping.
__global__ __launch_bounds__(256) void absmean_partial(const float4* __restrict__ wa,
                                                       const float4* __restrict__ wb,
                                                       double* __restrict__ partial) {
    __shared__ double red[256];
    const float4* w = (blockIdx.x < 1024) ? wa : wb;
    int base = (blockIdx.x & 1023) * 1024;  // in float4 units
    double s = 0.0;
#pragma unroll
    for (int k = 0; k < 4; ++k) {
        float4 v = w[base + (k << 8) + threadIdx.x];
        s += (double)fabsf(v.x) + (double)fabsf(v.y) +
             (double)fabsf(v.z) + (double)fabsf(v.w);
    }
    red[threadIdx.x] = s;
    __syncthreads();
    for (int off = 128; off > 0; off >>= 1) {
        if (threadIdx.x < off) red[threadIdx.x] += red[threadIdx.x + off];
        __syncthreads();
    }
    if (threadIdx.x == 0) partial[blockIdx.x] = red[0];
}

// Deterministic tree-sum of partials; scale = 1/clip(mean,1e-5) fp32.
__global__ __launch_bounds__(256) void finalize_scales(const double* __restrict__ part,
                                                       float* __restrict__ sc) {
    __shared__ double red[1024];
#pragma unroll 1
    for (int m = 0; m < 2; ++m) {
        const double* p = part + m * 1024;
        __syncthreads();
#pragma unroll
        for (int k = 0; k < 4; ++k) red[(k << 8) + threadIdx.x] = p[(k << 8) + threadIdx.x];
        __syncthreads();
        double s = red[threadIdx.x] + red[threadIdx.x + 256] +
                   red[threadIdx.x + 512] + red[threadIdx.x + 768];
        __syncthreads();
        red[threadIdx.x] = s;
        __syncthreads();
        for (int off = 128; off > 0; off >>= 1) {
            if (threadIdx.x < off) red[threadIdx.x] += red[threadIdx.x + off];
            __syncthreads();
        }
        if (threadIdx.x == 0) {
            double mean = red[0] / (double)WELEM;
            float mf = fmaxf((float)mean, 1e-5f);
            float scale = 1.0f / mf;
            sc[2 * m]     = scale;
            sc[2 * m + 1] = 1.0f / scale;
        }
    }
}

// Ternary-quantize both weight matrices in one launch:
// blocks [0,4096) -> w1 (slot 0), [4096,8192) -> w2 (slot 2).
__global__ __launch_bounds__(256) void quant_w(const float4* __restrict__ wa,
                                               const float4* __restrict__ wb,
                                               char4* __restrict__ qa,
                                               char4* __restrict__ qb,
                                               const float* __restrict__ sc) {
    bool second = blockIdx.x >= 4096;
    const float4* w = second ? wb : wa;
    char4* q = second ? qb : qa;
    float scale = sc[second ? 2 : 0];
    int i = (blockIdx.x & 4095) * 256 + threadIdx.x;
    float4 v = w[i];
    char4 o;
    o.x = (signed char)(int)fminf(fmaxf(rintf(v.x * scale), -1.f), 1.f);
    o.y = (signed char)(int)fminf(fmaxf(rintf(v.y * scale), -1.f), 1.f);
    o.z = (signed char)(int)fminf(fmaxf(rintf(v.z * scale), -1.f), 1.f);
    o.w = (signed char)(int)fminf(fmaxf(rintf(v.w * scale), -1.f), 1.f);
    q[i] = o;
}

// Per-token int8 absmax quantization of x (row length DM=1024), float4 loads
__global__ __launch_bounds__(256) void quant_x_kernel(const float4* __restrict__ x,
                                                      char4* __restrict__ q,
                                                      float* __restrict__ dq) {
    __shared__ float red[256];
    int t = blockIdx.x;
    float4 v = x[(size_t)t * 256 + threadIdx.x];
    float mx = fmaxf(fmaxf(fabsf(v.x), fabsf(v.y)), fmaxf(fabsf(v.z), fabsf(v.w)));
    red[threadIdx.x] = mx;
    __syncthreads();
    for (int off = 128; off > 0; off >>= 1) {
        if (threadIdx.x < off) red[threadIdx.x] = fmaxf(red[threadIdx.x], red[threadIdx.x + off]);
        __syncthreads();
    }
    float scale = 127.0f / fmaxf(red[0], 1e-5f);
    char4 o;
    o.x = (signed char)(int)fminf(fmaxf(rintf(v.x * scale), -128.f), 127.f);
    o.y = (signed char)(int)fminf(fmaxf(rintf(v.y * scale), -128.f), 127.f);
    o.z = (signed char)(int)fminf(fmaxf(rintf(v.z * scale), -128.f), 127.f);
    o.w = (signed char)(int)fminf(fmaxf(rintf(v.w * scale), -128.f), 127.f);
    q[(size_t)t * 256 + threadIdx.x] = o;
    if (threadIdx.x == 0) dq[t] = 1.0f / scale;
}

// Fused depthwise conv3 (+bias) + SiLU + per-token int8 quant over DH=4096.
// Register sliding window along t; 512 threads x 8 channels; row t+2
// prefetched before the reduction barrier; one barrier per row (ping-pong red).
__global__ __launch_bounds__(512) void conv_silu_quant(const float4* __restrict__ h,
                                                       const float4* __restrict__ cw,
                                                       const float4* __restrict__ cb,
                                                       char4* __restrict__ q,
                                                       float* __restrict__ dq) {
    __shared__ float red[2][8];
    const int tid = threadIdx.x;
    const int t0 = blockIdx.x * CT;
    const int s0 = t0 & (S_ - 1);      // CT | S_, block never straddles batches

    float4 w0[2], w1[2], w2[2], bb[2];
#pragma unroll
    for (int k = 0; k < 2; ++k) {
        int g = (k << 9) + tid;
        w0[k] = cw[3 * g]; w1[k] = cw[3 * g + 1]; w2[k] = cw[3 * g + 2];
        bb[k] = cb[g];
    }

    const float4 z4 = {0.f, 0.f, 0.f, 0.f};
    float4 pv[2], cu[2], nx[2], pf[2];
#pragma unroll
    for (int k = 0; k < 2; ++k) {
        int g = (k << 9) + tid;
        pv[k] = (s0 > 0) ? h[(size_t)(t0 - 1) * 1024 + g] : z4;
        cu[k] = h[(size_t)t0 * 1024 + g];
        nx[k] = h[(size_t)(t0 + 1) * 1024 + g];  // s0+1 < S_ always
    }

#pragma unroll
    for (int i = 0; i < CT; ++i) {
        const int t = t0 + i;
        bool hp2 = (s0 + i + 2) < S_;
#pragma unroll
        for (int k = 0; k < 2; ++k)
            pf[k] = hp2 ? h[(size_t)(t + 2) * 1024 + (k << 9) + tid] : z4;

        float4 v[2];
        float mx = 0.f;
#pragma unroll
        for (int k = 0; k < 2; ++k) {
            float4 a = pv[k], b = cu[k], c = nx[k];
            float4 y;
            y.x = w0[k].x * a.x + w0[k].y * b.x + w0[k].z * c.x + bb[k].x;
            y.y = w0[k].w * a.y + w1[k].x * b.y + w1[k].y * c.y + bb[k].y;
            y.z = w1[k].z * a.z + w1[k].w * b.z + w2[k].x * c.z + bb[k].z;
            y.w = w2[k].y * a.w + w2[k].z * b.w + w2[k].w * c.w + bb[k].w;
            float4 r;
            r.x = y.x / (1.0f + expf(-y.x));
            r.y = y.y / (1.0f + expf(-y.y));
            r.z = y.z / (1.0f + expf(-y.z));
            r.w = y.w / (1.0f + expf(-y.w));
            v[k] = r;
            mx = fmaxf(mx, fmaxf(fmaxf(fabsf(r.x), fabsf(r.y)), fmaxf(fabsf(r.z), fabsf(r.w))));
        }
#pragma unroll
        for (int off = 32; off > 0; off >>= 1)
            mx = fmaxf(mx, __shfl_down(mx, off, 64));
        if ((tid & 63) == 0) red[i & 1][tid >> 6] = mx;
        __syncthreads();
        float rmax = red[i & 1][0];
#pragma unroll
        for (int w = 1; w < 8; ++w) rmax = fmaxf(rmax, red[i & 1][w]);
        float scale = 127.0f / fmaxf(rmax, 1e-5f);
#pragma unroll
        for (int k = 0; k < 2; ++k) {
            char4 o;
            o.x = (signed char)(int)fminf(fmaxf(rintf(v[k].x * scale), -128.f), 127.f);
            o.y = (signed char)(int)fminf(fmaxf(rintf(v[k].y * scale), -128.f), 127.f);
            o.z = (signed char)(int)fminf(fmaxf(rintf(v[k].z * scale), -128.f), 127.f);
            o.w = (signed char)(int)fminf(fmaxf(rintf(v[k].w * scale), -128.f), 127.f);
            q[(size_t)t * 1024 + (k << 9) + tid] = o;
        }
        if (tid == 0) dq[t] = 1.0f / scale;
#pragma unroll
        for (int k = 0; k < 2; ++k) { pv[k] = cu[k]; cu[k] = nx[k]; nx[k] = pf[k]; }
    }
}

// int8 x ternary GEMM, direct-to-register (flatmm style):
// C[m,n] = (sum_k A[m,k]*B[n,k]) * rowdq[m] * sc[slot]
// NO LDS, NO __syncthreads. Each wave owns a 64x64 tile (4x4 grid of
// 16x16x64 i8 MFMAs) and loads its A/B fragments straight from global:
// lane l reads 16B at row (l&15), k-chunk (l>>4) -- coalesced dwordx4,
// served from L1/L2 (weights are 4MB, fully L2-resident; A rows reused 2x
// in-block). Without barriers there is no vmcnt(0) drain; the compiler
// interleaves loads for iter k+1 with MFMAs of iter k under fine vmcnt.
__global__ __launch_bounds__(256) void gemm_i8_direct(const int8_t* __restrict__ A,
                                                      const int8_t* __restrict__ Bm,
                                                      float* __restrict__ C,
                                                      const float* __restrict__ rowdq,
                                                      const float* __restrict__ sc, int slot,
                                                      int N, int K) {
    const int lane = threadIdx.x & 63;
    const int wave = threadIdx.x >> 6;
    const int mbase = (blockIdx.y << 7) + ((wave >> 1) << 6);  // wave's 64-row m origin
    const int nbase = (blockIdx.x << 7) + ((wave & 1) << 6);   // wave's 64-col n origin
    const int row = lane & 15;
    const int kq  = (lane >> 4) << 4;   // quad*16 byte offset within 64B k-slab

    const int8_t* Ab = A  + (size_t)(mbase + row) * K + kq;
    const int8_t* Bb = Bm + (size_t)(nbase + row) * K + kq;
    const size_t tstride = (size_t)16 * K;   // 16 rows

    v4i acc[4][4] = {};
    v4i af[2][4], bf[2][4];

    auto ldf = [&](int buf, int k0) {
#pragma unroll
        for (int i = 0; i < 4; ++i)
            af[buf][i] = *reinterpret_cast<const v4i*>(Ab + (size_t)i * tstride + k0);
#pragma unroll
        for (int j = 0; j < 4; ++j)
            bf[buf][j] = *reinterpret_cast<const v4i*>(Bb + (size_t)j * tstride + k0);
    };
    auto mm = [&](int buf) {
#pragma unroll
        for (int i = 0; i < 4; ++i)
#pragma unroll
            for (int j = 0; j < 4; ++j)
                acc[i][j] = __builtin_amdgcn_mfma_i32_16x16x64_i8(af[buf][i], bf[buf][j],
                                                                  acc[i][j], 0, 0, 0);
    };

    ldf(0, 0);
    for (int k0 = 0; k0 < K; k0 += 128) {   // K/64 iters, unrolled by 2
        if (k0 + 64 < K) ldf(1, k0 + 64);
        mm(0);
        if (k0 + 128 < K) ldf(0, k0 + 128);
        mm(1);
    }

    const float wdq = sc[slot];
    const int quad = lane >> 4;
    const int col  = lane & 15;
#pragma unroll
    for (int i = 0; i < 4; ++i) {
#pragma unroll
        for (int r = 0; r < 4; ++r) {
            int m = mbase + (i << 4) + (quad << 2) + r;   // C/D: row=(lane>>4)*4+reg
            float rs = rowdq[m] * wdq;
#pragma unroll
            for (int j = 0; j < 4; ++j) {
                int n = nbase + (j << 4) + col;           // C/D: col=lane&15
                C[(size_t)m * N + n] = (float)acc[i][j][r] * rs;
            }
        }
    }
}

// ---------------------------------------------------------------------------
extern "C" void kernel_launch(void* const* d_in, const int* in_sizes, int n_in,
                              void* d_out, int out_size, void* d_ws, size_t ws_size,
                              hipStream_t stream) {
    const float* x  = (const float*)d_in[0];  // [4,2048,1024]
    const float* w1 = (const float*)d_in[1];  // [4096,1024]
    const float* cw = (const float*)d_in[2];  // [4096,1,3]
    const float* cb = (const float*)d_in[3];  // [4096]
    const float* w2 = (const float*)d_in[4];  // [1024,4096]
    float* out = (float*)d_out;               // [4,2048,1024]
    char* ws = (char*)d_ws;

    // Workspace layout (16B-aligned); total ~185 MB
    double* part  = (double*)(ws + 0);          // 2048 doubles
    float*  sc    = (float*)(ws + 16384);       // {scale_w1, dq_w1, scale_w2, dq_w2}
    float*  dqx   = (float*)(ws + 16640);       // 8192 floats
    float*  dqh   = (float*)(ws + 49408);       // 8192 floats
    int8_t* qw1   = (int8_t*)(ws + 82176);      // 4 MB
    int8_t* qw2   = (int8_t*)(ws + 4276480);    // 4 MB
    int8_t* qx    = (int8_t*)(ws + 8470784);    // 8 MB
    int8_t* qh    = (int8_t*)(ws + 16859392);   // 32 MB
    float*  h     = (float*)(ws + 50413824);    // 128 MB

    absmean_partial<<<2048, 256, 0, stream>>>((const float4*)w1, (const float4*)w2, part);
    finalize_scales<<<1, 256, 0, stream>>>(part, sc);
    quant_w<<<8192, 256, 0, stream>>>((const float4*)w1, (const float4*)w2,
                                      (char4*)qw1, (char4*)qw2, sc);
    quant_x_kernel<<<NTOK, 256, 0, stream>>>((const float4*)x, (char4*)qx, dqx);

    // GEMM1: M=8192, N=4096, K=1024; 128x128 blocks
    dim3 g1(DH / 128, NTOK / 128);
    gemm_i8_direct<<<g1, 256, 0, stream>>>(qx, qw1, h, dqx, sc, 1, DH, DM);

    conv_silu_quant<<<NTOK / CT, 512, 0, stream>>>((const float4*)h, (const float4*)cw,
                                                   (const float4*)cb, (char4*)qh, dqh);

    // GEMM2: M=8192, N=1024, K=4096; 128x128 blocks
    dim3 g2(DM / 128, NTOK / 128);
    gemm_i8_direct<<<g2, 256, 0, stream>>>(qh, qw2, out, dqh, sc, 3, DM, DH);
}

// Round 6
// 281.837 us; speedup vs baseline: 1.4510x; 1.4510x over previous
//
#include <hip/hip_runtime.h>
#include <cstdint>

// Problem sizes (fixed by reference)
#define S_    2048
#define DM    1024
#define DH    4096
#define NTOK  8192     // B*S = 4*2048
#define WELEM 4194304  // 4096*1024 elements in each weight matrix
#define CT    8        // tokens per conv block
#define NS    3        // LDS pipeline stages in gemm

typedef int v4i __attribute__((ext_vector_type(4)));

// async global->LDS, 16B per lane, dest = ldsbase + lane*16 (wave-uniform base)
#define GLOAD_LDS16(g, l)                                                   \
    __builtin_amdgcn_global_load_lds(                                       \
        (const __attribute__((address_space(1))) void*)(g),                 \
        (__attribute__((address_space(3))) void*)(l), 16, 0, 0)

// s_waitcnt immediates (gfx9 encoding): vmcnt[3:0]|[15:14], exp[6:4], lgkm[11:8]
#define WAITCNT_VM16 0x4F70   // vmcnt<=16, exp/lgkm don't-care
#define WAITCNT_VM0  0x0F70   // vmcnt<=0

// ---------------------------------------------------------------------------
// Per-block partial sums of |w| in fp64, both matrices in one launch.
__global__ __launch_bounds__(256) void absmean_partial(const float4* __restrict__ wa,
                                                       const float4* __restrict__ wb,
                                                       double* __restrict__ partial) {
    __shared__ double red[256];
    const float4* w = (blockIdx.x < 1024) ? wa : wb;
    int base = (blockIdx.x & 1023) * 1024;  // in float4 units
    double s = 0.0;
#pragma unroll
    for (int k = 0; k < 4; ++k) {
        float4 v = w[base + (k << 8) + threadIdx.x];
        s += (double)fabsf(v.x) + (double)fabsf(v.y) +
             (double)fabsf(v.z) + (double)fabsf(v.w);
    }
    red[threadIdx.x] = s;
    __syncthreads();
    for (int off = 128; off > 0; off >>= 1) {
        if (threadIdx.x < off) red[threadIdx.x] += red[threadIdx.x + off];
        __syncthreads();
    }
    if (threadIdx.x == 0) partial[blockIdx.x] = red[0];
}

// Deterministic tree-sum of partials; scale = 1/clip(mean,1e-5) fp32.
__global__ __launch_bounds__(256) void finalize_scales(const double* __restrict__ part,
                                                       float* __restrict__ sc) {
    __shared__ double red[1024];
#pragma unroll 1
    for (int m = 0; m < 2; ++m) {
        const double* p = part + m * 1024;
        __syncthreads();
#pragma unroll
        for (int k = 0; k < 4; ++k) red[(k << 8) + threadIdx.x] = p[(k << 8) + threadIdx.x];
        __syncthreads();
        double s = red[threadIdx.x] + red[threadIdx.x + 256] +
                   red[threadIdx.x + 512] + red[threadIdx.x + 768];
        __syncthreads();
        red[threadIdx.x] = s;
        __syncthreads();
        for (int off = 128; off > 0; off >>= 1) {
            if (threadIdx.x < off) red[threadIdx.x] += red[threadIdx.x + off];
            __syncthreads();
        }
        if (threadIdx.x == 0) {
            double mean = red[0] / (double)WELEM;
            float mf = fmaxf((float)mean, 1e-5f);
            float scale = 1.0f / mf;
            sc[2 * m]     = scale;
            sc[2 * m + 1] = 1.0f / scale;
        }
    }
}

// Ternary-quantize both weight matrices in one launch.
__global__ __launch_bounds__(256) void quant_w(const float4* __restrict__ wa,
                                               const float4* __restrict__ wb,
                                               char4* __restrict__ qa,
                                               char4* __restrict__ qb,
                                               const float* __restrict__ sc) {
    bool second = blockIdx.x >= 4096;
    const float4* w = second ? wb : wa;
    char4* q = second ? qb : qa;
    float scale = sc[second ? 2 : 0];
    int i = (blockIdx.x & 4095) * 256 + threadIdx.x;
    float4 v = w[i];
    char4 o;
    o.x = (signed char)(int)fminf(fmaxf(rintf(v.x * scale), -1.f), 1.f);
    o.y = (signed char)(int)fminf(fmaxf(rintf(v.y * scale), -1.f), 1.f);
    o.z = (signed char)(int)fminf(fmaxf(rintf(v.z * scale), -1.f), 1.f);
    o.w = (signed char)(int)fminf(fmaxf(rintf(v.w * scale), -1.f), 1.f);
    q[i] = o;
}

// Per-token int8 absmax quantization of x (row length DM=1024), float4 loads
__global__ __launch_bounds__(256) void quant_x_kernel(const float4* __restrict__ x,
                                                      char4* __restrict__ q,
                                                      float* __restrict__ dq) {
    __shared__ float red[256];
    int t = blockIdx.x;
    float4 v = x[(size_t)t * 256 + threadIdx.x];
    float mx = fmaxf(fmaxf(fabsf(v.x), fabsf(v.y)), fmaxf(fabsf(v.z), fabsf(v.w)));
    red[threadIdx.x] = mx;
    __syncthreads();
    for (int off = 128; off > 0; off >>= 1) {
        if (threadIdx.x < off) red[threadIdx.x] = fmaxf(red[threadIdx.x], red[threadIdx.x + off]);
        __syncthreads();
    }
    float scale = 127.0f / fmaxf(red[0], 1e-5f);
    char4 o;
    o.x = (signed char)(int)fminf(fmaxf(rintf(v.x * scale), -128.f), 127.f);
    o.y = (signed char)(int)fminf(fmaxf(rintf(v.y * scale), -128.f), 127.f);
    o.z = (signed char)(int)fminf(fmaxf(rintf(v.z * scale), -128.f), 127.f);
    o.w = (signed char)(int)fminf(fmaxf(rintf(v.w * scale), -128.f), 127.f);
    q[(size_t)t * 256 + threadIdx.x] = o;
    if (threadIdx.x == 0) dq[t] = 1.0f / scale;
}

// Fused depthwise conv3 (+bias) + SiLU + per-token int8 quant over DH=4096.
// Register sliding window along t; 512 threads x 8 channels; row t+2
// prefetched before the reduction barrier; one barrier per row.
__global__ __launch_bounds__(512) void conv_silu_quant(const float4* __restrict__ h,
                                                       const float4* __restrict__ cw,
                                                       const float4* __restrict__ cb,
                                                       char4* __restrict__ q,
                                                       float* __restrict__ dq) {
    __shared__ float red[2][8];
    const int tid = threadIdx.x;
    const int t0 = blockIdx.x * CT;
    const int s0 = t0 & (S_ - 1);      // CT | S_, block never straddles batches

    float4 w0[2], w1[2], w2[2], bb[2];
#pragma unroll
    for (int k = 0; k < 2; ++k) {
        int g = (k << 9) + tid;
        w0[k] = cw[3 * g]; w1[k] = cw[3 * g + 1]; w2[k] = cw[3 * g + 2];
        bb[k] = cb[g];
    }

    const float4 z4 = {0.f, 0.f, 0.f, 0.f};
    float4 pv[2], cu[2], nx[2], pf[2];
#pragma unroll
    for (int k = 0; k < 2; ++k) {
        int g = (k << 9) + tid;
        pv[k] = (s0 > 0) ? h[(size_t)(t0 - 1) * 1024 + g] : z4;
        cu[k] = h[(size_t)t0 * 1024 + g];
        nx[k] = h[(size_t)(t0 + 1) * 1024 + g];  // s0+1 < S_ always
    }

#pragma unroll
    for (int i = 0; i < CT; ++i) {
        const int t = t0 + i;
        bool hp2 = (s0 + i + 2) < S_;
#pragma unroll
        for (int k = 0; k < 2; ++k)
            pf[k] = hp2 ? h[(size_t)(t + 2) * 1024 + (k << 9) + tid] : z4;

        float4 v[2];
        float mx = 0.f;
#pragma unroll
        for (int k = 0; k < 2; ++k) {
            float4 a = pv[k], b = cu[k], c = nx[k];
            float4 y;
            y.x = w0[k].x * a.x + w0[k].y * b.x + w0[k].z * c.x + bb[k].x;
            y.y = w0[k].w * a.y + w1[k].x * b.y + w1[k].y * c.y + bb[k].y;
            y.z = w1[k].z * a.z + w1[k].w * b.z + w2[k].x * c.z + bb[k].z;
            y.w = w2[k].y * a.w + w2[k].z * b.w + w2[k].w * c.w + bb[k].w;
            float4 r;
            r.x = y.x / (1.0f + expf(-y.x));
            r.y = y.y / (1.0f + expf(-y.y));
            r.z = y.z / (1.0f + expf(-y.z));
            r.w = y.w / (1.0f + expf(-y.w));
            v[k] = r;
            mx = fmaxf(mx, fmaxf(fmaxf(fabsf(r.x), fabsf(r.y)), fmaxf(fabsf(r.z), fabsf(r.w))));
        }
#pragma unroll
        for (int off = 32; off > 0; off >>= 1)
            mx = fmaxf(mx, __shfl_down(mx, off, 64));
        if ((tid & 63) == 0) red[i & 1][tid >> 6] = mx;
        __syncthreads();
        float rmax = red[i & 1][0];
#pragma unroll
        for (int w = 1; w < 8; ++w) rmax = fmaxf(rmax, red[i & 1][w]);
        float scale = 127.0f / fmaxf(rmax, 1e-5f);
#pragma unroll
        for (int k = 0; k < 2; ++k) {
            char4 o;
            o.x = (signed char)(int)fminf(fmaxf(rintf(v[k].x * scale), -128.f), 127.f);
            o.y = (signed char)(int)fminf(fmaxf(rintf(v[k].y * scale), -128.f), 127.f);
            o.z = (signed char)(int)fminf(fmaxf(rintf(v[k].z * scale), -128.f), 127.f);
            o.w = (signed char)(int)fminf(fmaxf(rintf(v[k].w * scale), -128.f), 127.f);
            q[(size_t)t * 1024 + (k << 9) + tid] = o;
        }
        if (tid == 0) dq[t] = 1.0f / scale;
#pragma unroll
        for (int k = 0; k < 2; ++k) { pv[k] = cu[k]; cu[k] = nx[k]; nx[k] = pf[k]; }
    }
}

// int8 x ternary GEMM, producer-consumer wave-specialized (no K-loop barrier):
// C[m,n] = (sum_k A[m,k]*B[n,k]) * rowdq[m] * sc[slot]
// Block = 5 waves. Wave 4 = producer: issues 16 global_load_lds per stage
// into a 3-stage LDS ring, signals readiness via LDS flag after waiting ONLY
// its own oldest stage (s_waitcnt vmcnt(16) -- lookahead stays in flight,
// which the __syncthreads structure cannot express). Waves 0-3 = consumers
// (2x2, 64x64 tiles each, 4x4 mfma_i32_16x16x64_i8): spin on flag (acquire),
// ds_read fragments, acq-rel increment of consume counter (ring recycle),
// MFMA. Single __syncthreads only at init. Deadlock-free: workgroup waves
// are co-resident; all waits are on monotone counters with matched totals.
__global__ __launch_bounds__(320) void gemm_i8_pc(const int8_t* __restrict__ A,
                                                  const int8_t* __restrict__ Bm,
                                                  float* __restrict__ C,
                                                  const float* __restrict__ rowdq,
                                                  const float* __restrict__ sc, int slot,
                                                  int N, int K) {
    __shared__ __align__(16) int8_t Alds[NS][8192];
    __shared__ __align__(16) int8_t Blds[NS][8192];
    __shared__ int flag[NS];
    __shared__ int cnt[NS];
    const int tid  = threadIdx.x;
    const int lane = tid & 63;
    const int wave = tid >> 6;
    const int mbase = blockIdx.y << 7;
    const int nbase = blockIdx.x << 7;
    const int niter = K >> 6;

    if (tid < NS) { flag[tid] = 0; cnt[tid] = 0; }
    __syncthreads();

    if (wave == 4) {
        // ---------------- producer ----------------
        const int r_l = lane >> 2;
        const int c_l = ((lane & 3) - ((lane >> 3) & 3)) & 3;
        const int8_t* Agb = A  + (size_t)(mbase + r_l) * K + c_l * 16;
        const int8_t* Bgb = Bm + (size_t)(nbase + r_l) * K + c_l * 16;
        const size_t ts = (size_t)16 * K;   // 16-row tile stride

        auto issue = [&](int j) {
            const int s = j % NS;
            const int k0 = j << 6;
#pragma unroll
            for (int t = 0; t < 8; ++t)
                GLOAD_LDS16(Agb + (size_t)t * ts + k0, &Alds[s][t << 10]);
#pragma unroll
            for (int t = 0; t < 8; ++t)
                GLOAD_LDS16(Bgb + (size_t)t * ts + k0, &Blds[s][t << 10]);
        };

        issue(0);
        if (niter > 1) issue(1);
        for (int it = 0; it < niter; ++it) {
            if (it + 1 < niter) __builtin_amdgcn_s_waitcnt(WAITCNT_VM16);
            else                __builtin_amdgcn_s_waitcnt(WAITCNT_VM0);
            __hip_atomic_store(&flag[it % NS], it + 1,
                               __ATOMIC_RELEASE, __HIP_MEMORY_SCOPE_WORKGROUP);
            const int j = it + 2;
            if (j < niter) {
                const int s = j % NS, need = 4 * (j / NS);
                while (__hip_atomic_load(&cnt[s], __ATOMIC_ACQUIRE,
                                         __HIP_MEMORY_SCOPE_WORKGROUP) < need)
                    __builtin_amdgcn_s_sleep(1);
                issue(j);
            }
        }
        return;
    }

    // ---------------- consumers (waves 0-3) ----------------
    const int wm4 = (wave >> 1) << 2;   // first of 4 m-tiles
    const int wn4 = (wave & 1) << 2;    // first of 4 n-tiles
    const int m_l = lane & 15, q_l = lane >> 4;
    const int fro = (4 * m_l + ((q_l + (m_l >> 1)) & 3)) << 4;

    v4i acc[4][4] = {};
    for (int it = 0; it < niter; ++it) {
        const int s = it % NS;
        while (__hip_atomic_load(&flag[s], __ATOMIC_ACQUIRE,
                                 __HIP_MEMORY_SCOPE_WORKGROUP) < it + 1)
            __builtin_amdgcn_s_sleep(1);
        v4i af[4], bf[4];
#pragma unroll
        for (int i = 0; i < 4; ++i)
            af[i] = *reinterpret_cast<const v4i*>(&Alds[s][fro + ((wm4 + i) << 10)]);
#pragma unroll
        for (int j = 0; j < 4; ++j)
            bf[j] = *reinterpret_cast<const v4i*>(&Blds[s][fro + ((wn4 + j) << 10)]);
        // acq_rel: orders the ds_reads above before the counter bump
        __hip_atomic_fetch_add(&cnt[s], 1, __ATOMIC_ACQ_REL, __HIP_MEMORY_SCOPE_WORKGROUP);
#pragma unroll
        for (int i = 0; i < 4; ++i)
#pragma unroll
            for (int j = 0; j < 4; ++j)
                acc[i][j] = __builtin_amdgcn_mfma_i32_16x16x64_i8(af[i], bf[j], acc[i][j], 0, 0, 0);
    }

    const float wdq = sc[slot];
    const int quad = lane >> 4;
    const int col  = lane & 15;
#pragma unroll
    for (int i = 0; i < 4; ++i) {
#pragma unroll
        for (int r = 0; r < 4; ++r) {
            int m = mbase + ((wm4 + i) << 4) + (quad << 2) + r;  // C/D: row=(lane>>4)*4+reg
            float rs = rowdq[m] * wdq;
#pragma unroll
            for (int j = 0; j < 4; ++j) {
                int n = nbase + ((wn4 + j) << 4) + col;          // C/D: col=lane&15
                C[(size_t)m * N + n] = (float)acc[i][j][r] * rs;
            }
        }
    }
}

// ---------------------------------------------------------------------------
extern "C" void kernel_launch(void* const* d_in, const int* in_sizes, int n_in,
                              void* d_out, int out_size, void* d_ws, size_t ws_size,
                              hipStream_t stream) {
    const float* x  = (const float*)d_in[0];  // [4,2048,1024]
    const float* w1 = (const float*)d_in[1];  // [4096,1024]
    const float* cw = (const float*)d_in[2];  // [4096,1,3]
    const float* cb = (const float*)d_in[3];  // [4096]
    const float* w2 = (const float*)d_in[4];  // [1024,4096]
    float* out = (float*)d_out;               // [4,2048,1024]
    char* ws = (char*)d_ws;

    // Workspace layout (16B-aligned); total ~185 MB
    double* part  = (double*)(ws + 0);          // 2048 doubles
    float*  sc    = (float*)(ws + 16384);       // {scale_w1, dq_w1, scale_w2, dq_w2}
    float*  dqx   = (float*)(ws + 16640);       // 8192 floats
    float*  dqh   = (float*)(ws + 49408);       // 8192 floats
    int8_t* qw1   = (int8_t*)(ws + 82176);      // 4 MB
    int8_t* qw2   = (int8_t*)(ws + 4276480);    // 4 MB
    int8_t* qx    = (int8_t*)(ws + 8470784);    // 8 MB
    int8_t* qh    = (int8_t*)(ws + 16859392);   // 32 MB
    float*  h     = (float*)(ws + 50413824);    // 128 MB

    absmean_partial<<<2048, 256, 0, stream>>>((const float4*)w1, (const float4*)w2, part);
    finalize_scales<<<1, 256, 0, stream>>>(part, sc);
    quant_w<<<8192, 256, 0, stream>>>((const float4*)w1, (const float4*)w2,
                                      (char4*)qw1, (char4*)qw2, sc);
    quant_x_kernel<<<NTOK, 256, 0, stream>>>((const float4*)x, (char4*)qx, dqx);

    // GEMM1: M=8192, N=4096, K=1024; 128x128 blocks, 5 waves (4 consumers + 1 producer)
    dim3 g1(DH / 128, NTOK / 128);
    gemm_i8_pc<<<g1, 320, 0, stream>>>(qx, qw1, h, dqx, sc, 1, DH, DM);

    conv_silu_quant<<<NTOK / CT, 512, 0, stream>>>((const float4*)h, (const float4*)cw,
                                                   (const float4*)cb, (char4*)qh, dqh);

    // GEMM2: M=8192, N=1024, K=4096
    dim3 g2(DM / 128, NTOK / 128);
    gemm_i8_pc<<<g2, 320, 0, stream>>>(qh, qw2, out, dqh, sc, 3, DM, DH);
}

// Round 7
// 273.508 us; speedup vs baseline: 1.4951x; 1.0305x over previous
//
#include <hip/hip_runtime.h>
#include <cstdint>

// Problem sizes (fixed by reference)
#define S_    2048
#define DM    1024
#define DH    4096
#define NTOK  8192     // B*S = 4*2048
#define WELEM 4194304  // 4096*1024 elements in each weight matrix
#define CT    8        // tokens per conv block
#define NS    3        // LDS pipeline stages in gemm

typedef int v4i __attribute__((ext_vector_type(4)));
typedef _Float16 half8 __attribute__((ext_vector_type(8)));
typedef char char8v __attribute__((ext_vector_type(8)));

// async global->LDS, 16B per lane, dest = ldsbase + lane*16 (wave-uniform base)
#define GLOAD_LDS16(g, l)                                                   \
    __builtin_amdgcn_global_load_lds(                                       \
        (const __attribute__((address_space(1))) void*)(g),                 \
        (__attribute__((address_space(3))) void*)(l), 16, 0, 0)

// s_waitcnt immediates (gfx9 enc): vmcnt bits[3:0]|[15:14], exp[6:4], lgkm[11:8]
#define WAITCNT_VM16  0x4F70   // vmcnt<=16, exp/lgkm don't-care
#define WAITCNT_VM0   0x0F70   // vmcnt<=0,  exp/lgkm don't-care
#define WAITCNT_LGKM0 0xC07F   // lgkmcnt<=0, vm/exp don't-care

// ---------------------------------------------------------------------------
// Per-block partial sums of |w| in fp64, both matrices in one launch.
__global__ __launch_bounds__(256) void absmean_partial(const float4* __restrict__ wa,
                                                       const float4* __restrict__ wb,
                                                       double* __restrict__ partial) {
    __shared__ double red[256];
    const float4* w = (blockIdx.x < 1024) ? wa : wb;
    int base = (blockIdx.x & 1023) * 1024;  // in float4 units
    double s = 0.0;
#pragma unroll
    for (int k = 0; k < 4; ++k) {
        float4 v = w[base + (k << 8) + threadIdx.x];
        s += (double)fabsf(v.x) + (double)fabsf(v.y) +
             (double)fabsf(v.z) + (double)fabsf(v.w);
    }
    red[threadIdx.x] = s;
    __syncthreads();
    for (int off = 128; off > 0; off >>= 1) {
        if (threadIdx.x < off) red[threadIdx.x] += red[threadIdx.x + off];
        __syncthreads();
    }
    if (threadIdx.x == 0) partial[blockIdx.x] = red[0];
}

// Deterministic tree-sum of partials; scale = 1/clip(mean,1e-5) fp32.
__global__ __launch_bounds__(256) void finalize_scales(const double* __restrict__ part,
                                                       float* __restrict__ sc) {
    __shared__ double red[1024];
#pragma unroll 1
    for (int m = 0; m < 2; ++m) {
        const double* p = part + m * 1024;
        __syncthreads();
#pragma unroll
        for (int k = 0; k < 4; ++k) red[(k << 8) + threadIdx.x] = p[(k << 8) + threadIdx.x];
        __syncthreads();
        double s = red[threadIdx.x] + red[threadIdx.x + 256] +
                   red[threadIdx.x + 512] + red[threadIdx.x + 768];
        __syncthreads();
        red[threadIdx.x] = s;
        __syncthreads();
        for (int off = 128; off > 0; off >>= 1) {
            if (threadIdx.x < off) red[threadIdx.x] += red[threadIdx.x + off];
            __syncthreads();
        }
        if (threadIdx.x == 0) {
            double mean = red[0] / (double)WELEM;
            float mf = fmaxf((float)mean, 1e-5f);
            float scale = 1.0f / mf;
            sc[2 * m]     = scale;
            sc[2 * m + 1] = 1.0f / scale;
        }
    }
}

// One launch: blocks [0,8192) ternary-quantize w1/w2; [8192,16384) int8-quantize x.
__global__ __launch_bounds__(256) void quant_all(const float4* __restrict__ w1,
                                                 const float4* __restrict__ w2,
                                                 const float4* __restrict__ x,
                                                 char4* __restrict__ qw1,
                                                 char4* __restrict__ qw2,
                                                 char4* __restrict__ qx,
                                                 float* __restrict__ dqx,
                                                 const float* __restrict__ sc) {
    __shared__ float red[256];
    if (blockIdx.x < 8192) {
        bool second = blockIdx.x >= 4096;
        const float4* w = second ? w2 : w1;
        char4* q = second ? qw2 : qw1;
        float scale = sc[second ? 2 : 0];
        int i = (blockIdx.x & 4095) * 256 + threadIdx.x;
        float4 v = w[i];
        char4 o;
        o.x = (signed char)(int)fminf(fmaxf(rintf(v.x * scale), -1.f), 1.f);
        o.y = (signed char)(int)fminf(fmaxf(rintf(v.y * scale), -1.f), 1.f);
        o.z = (signed char)(int)fminf(fmaxf(rintf(v.z * scale), -1.f), 1.f);
        o.w = (signed char)(int)fminf(fmaxf(rintf(v.w * scale), -1.f), 1.f);
        q[i] = o;
    } else {
        int t = blockIdx.x - 8192;
        float4 v = x[(size_t)t * 256 + threadIdx.x];
        float mx = fmaxf(fmaxf(fabsf(v.x), fabsf(v.y)), fmaxf(fabsf(v.z), fabsf(v.w)));
        red[threadIdx.x] = mx;
        __syncthreads();
        for (int off = 128; off > 0; off >>= 1) {
            if (threadIdx.x < off) red[threadIdx.x] = fmaxf(red[threadIdx.x], red[threadIdx.x + off]);
            __syncthreads();
        }
        float scale = 127.0f / fmaxf(red[0], 1e-5f);
        char4 o;
        o.x = (signed char)(int)fminf(fmaxf(rintf(v.x * scale), -128.f), 127.f);
        o.y = (signed char)(int)fminf(fmaxf(rintf(v.y * scale), -128.f), 127.f);
        o.z = (signed char)(int)fminf(fmaxf(rintf(v.z * scale), -128.f), 127.f);
        o.w = (signed char)(int)fminf(fmaxf(rintf(v.w * scale), -128.f), 127.f);
        qx[(size_t)t * 256 + threadIdx.x] = o;
        if (threadIdx.x == 0) dqx[t] = 1.0f / scale;
    }
}

// Fused depthwise conv3 (+bias) + SiLU + per-token int8 quant over DH=4096.
// h is fp16 (written by GEMM1's epilogue): 512 threads x 8 channels, one 16B
// half8 load per row per thread. Register sliding window along t, row t+2
// prefetched before the reduction barrier; one barrier per row.
__global__ __launch_bounds__(512) void conv_silu_quant(const half8* __restrict__ h,
                                                       const float4* __restrict__ cwv,
                                                       const float4* __restrict__ cbv,
                                                       char8v* __restrict__ q,
                                                       float* __restrict__ dq) {
    __shared__ float red[2][8];
    const int tid = threadIdx.x;
    const int t0 = blockIdx.x * CT;
    const int s0 = t0 & (S_ - 1);      // CT | S_, block never straddles batches

    // conv weights for this thread's 8 channels [8*tid, 8*tid+8)
    float wc[24], bs[8];
    {
        float4 tmp;
#pragma unroll
        for (int i = 0; i < 6; ++i) {
            tmp = cwv[tid * 6 + i];
            wc[4 * i] = tmp.x; wc[4 * i + 1] = tmp.y; wc[4 * i + 2] = tmp.z; wc[4 * i + 3] = tmp.w;
        }
        tmp = cbv[tid * 2];     bs[0] = tmp.x; bs[1] = tmp.y; bs[2] = tmp.z; bs[3] = tmp.w;
        tmp = cbv[tid * 2 + 1]; bs[4] = tmp.x; bs[5] = tmp.y; bs[6] = tmp.z; bs[7] = tmp.w;
    }

    auto ldrow = [&](int t, bool valid, float* dst) {
        if (valid) {
            half8 raw = h[(size_t)t * 512 + tid];
#pragma unroll
            for (int e = 0; e < 8; ++e) dst[e] = (float)raw[e];
        } else {
#pragma unroll
            for (int e = 0; e < 8; ++e) dst[e] = 0.f;
        }
    };

    float pv[8], cu[8], nx[8], pf[8];
    ldrow(t0 - 1, s0 > 0, pv);
    ldrow(t0, true, cu);
    ldrow(t0 + 1, true, nx);   // s0+1 < S_ always (CT | S_)

#pragma unroll
    for (int i = 0; i < CT; ++i) {
        const int t = t0 + i;
        ldrow(t + 2, (s0 + i + 2) < S_, pf);

        float v[8];
        float mx = 0.f;
#pragma unroll
        for (int e = 0; e < 8; ++e) {
            float y = wc[3 * e] * pv[e] + wc[3 * e + 1] * cu[e] + wc[3 * e + 2] * nx[e] + bs[e];
            float r = y / (1.0f + expf(-y));
            v[e] = r;
            mx = fmaxf(mx, fabsf(r));
        }
#pragma unroll
        for (int off = 32; off > 0; off >>= 1)
            mx = fmaxf(mx, __shfl_down(mx, off, 64));
        if ((tid & 63) == 0) red[i & 1][tid >> 6] = mx;
        __syncthreads();
        float rmax = red[i & 1][0];
#pragma unroll
        for (int w = 1; w < 8; ++w) rmax = fmaxf(rmax, red[i & 1][w]);
        float scale = 127.0f / fmaxf(rmax, 1e-5f);
        char8v o;
#pragma unroll
        for (int e = 0; e < 8; ++e)
            o[e] = (signed char)(int)fminf(fmaxf(rintf(v[e] * scale), -128.f), 127.f);
        q[(size_t)t * 512 + tid] = o;
        if (tid == 0) dq[t] = 1.0f / scale;
#pragma unroll
        for (int e = 0; e < 8; ++e) { pv[e] = cu[e]; cu[e] = nx[e]; nx[e] = pf[e]; }
    }
}

// int8 x ternary GEMM, producer-consumer wave-specialized (no K-loop barrier):
// C[m,n] = (sum_k A[m,k]*B[n,k]) * rowdq[m] * sc[slot]
// Block = 5 waves. Wave 4 = producer: 16 global_load_lds per stage into a
// 3-stage ring; signals with a RELAXED ds_write after a manual
// s_waitcnt vmcnt(16) -- RELAXED is essential: a RELEASE store makes the
// compiler emit vmcnt(0), draining the lookahead (r6's silent failure mode).
// Consumers (waves 0-3, 64x64 tiles, 4x4 mfma_i32_16x16x64_i8): spin on flag
// (acquire), ds_read frags, explicit lgkmcnt(0), then LANE 0 ONLY bumps the
// consumption counter (r6 had all 64 lanes adding: 64-way serialized LDS
// atomics AND an inflated count that broke the ring-recycle guard).
// Producer waits cnt[s] >= 4*round before reusing a stage. Deadlock-free:
// co-resident waves, monotone counters, matched totals.
template <typename OutT>
__global__ __launch_bounds__(320) void gemm_i8_pc(const int8_t* __restrict__ A,
                                                  const int8_t* __restrict__ Bm,
                                                  OutT* __restrict__ C,
                                                  const float* __restrict__ rowdq,
                                                  const float* __restrict__ sc, int slot,
                                                  int N, int K) {
    __shared__ __align__(16) int8_t Alds[NS][8192];
    __shared__ __align__(16) int8_t Blds[NS][8192];
    __shared__ int flag[NS];
    __shared__ int cnt[NS];
    const int tid  = threadIdx.x;
    const int lane = tid & 63;
    const int wave = tid >> 6;
    const int mbase = blockIdx.y << 7;
    const int nbase = blockIdx.x << 7;
    const int niter = K >> 6;

    if (tid < NS) { flag[tid] = 0; cnt[tid] = 0; }
    __syncthreads();

    if (wave == 4) {
        // ---------------- producer ----------------
        const int r_l = lane >> 2;
        const int c_l = ((lane & 3) - ((lane >> 3) & 3)) & 3;
        const int8_t* Agb = A  + (size_t)(mbase + r_l) * K + c_l * 16;
        const int8_t* Bgb = Bm + (size_t)(nbase + r_l) * K + c_l * 16;
        const size_t ts = (size_t)16 * K;   // 16-row tile stride

        auto issue = [&](int j) {
            const int s = j % NS;
            const int k0 = j << 6;
#pragma unroll
            for (int t = 0; t < 8; ++t)
                GLOAD_LDS16(Agb + (size_t)t * ts + k0, &Alds[s][t << 10]);
#pragma unroll
            for (int t = 0; t < 8; ++t)
                GLOAD_LDS16(Bgb + (size_t)t * ts + k0, &Blds[s][t << 10]);
        };

        issue(0);
        if (niter > 1) issue(1);
        for (int it = 0; it < niter; ++it) {
            if (it + 1 < niter) __builtin_amdgcn_s_waitcnt(WAITCNT_VM16);
            else                __builtin_amdgcn_s_waitcnt(WAITCNT_VM0);
            __hip_atomic_store(&flag[it % NS], it + 1,
                               __ATOMIC_RELAXED, __HIP_MEMORY_SCOPE_WORKGROUP);
            const int j = it + 2;
            if (j < niter) {
                const int s2 = j % NS, need = 4 * (j / NS);
                while (__hip_atomic_load(&cnt[s2], __ATOMIC_RELAXED,
                                         __HIP_MEMORY_SCOPE_WORKGROUP) < need)
                    __builtin_amdgcn_s_sleep(1);
                issue(j);
            }
        }
        return;
    }

    // ---------------- consumers (waves 0-3) ----------------
    const int wm4 = (wave >> 1) << 2;   // first of 4 m-tiles
    const int wn4 = (wave & 1) << 2;    // first of 4 n-tiles
    const int m_l = lane & 15, q_l = lane >> 4;
    const int fro = (4 * m_l + ((q_l + (m_l >> 1)) & 3)) << 4;

    v4i acc[4][4] = {};
    for (int it = 0; it < niter; ++it) {
        const int s = it % NS;
        while (__hip_atomic_load(&flag[s], __ATOMIC_ACQUIRE,
                                 __HIP_MEMORY_SCOPE_WORKGROUP) < it + 1)
            __builtin_amdgcn_s_sleep(1);
        v4i af[4], bf[4];
#pragma unroll
        for (int i = 0; i < 4; ++i)
            af[i] = *reinterpret_cast<const v4i*>(&Alds[s][fro + ((wm4 + i) << 10)]);
#pragma unroll
        for (int j = 0; j < 4; ++j)
            bf[j] = *reinterpret_cast<const v4i*>(&Blds[s][fro + ((wn4 + j) << 10)]);
        __builtin_amdgcn_s_waitcnt(WAITCNT_LGKM0);   // wave's frag reads complete
        if (lane == 0)
            __hip_atomic_fetch_add(&cnt[s], 1, __ATOMIC_RELAXED,
                                   __HIP_MEMORY_SCOPE_WORKGROUP);
#pragma unroll
        for (int i = 0; i < 4; ++i)
#pragma unroll
            for (int j = 0; j < 4; ++j)
                acc[i][j] = __builtin_amdgcn_mfma_i32_16x16x64_i8(af[i], bf[j], acc[i][j], 0, 0, 0);
    }

    const float wdq = sc[slot];
    const int quad = lane >> 4;
    const int col  = lane & 15;
#pragma unroll
    for (int i = 0; i < 4; ++i) {
#pragma unroll
        for (int r = 0; r < 4; ++r) {
            int m = mbase + ((wm4 + i) << 4) + (quad << 2) + r;  // C/D: row=(lane>>4)*4+reg
            float rs = rowdq[m] * wdq;
#pragma unroll
            for (int j = 0; j < 4; ++j) {
                int n = nbase + ((wn4 + j) << 4) + col;          // C/D: col=lane&15
                C[(size_t)m * N + n] = (OutT)((float)acc[i][j][r] * rs);
            }
        }
    }
}

// ---------------------------------------------------------------------------
extern "C" void kernel_launch(void* const* d_in, const int* in_sizes, int n_in,
                              void* d_out, int out_size, void* d_ws, size_t ws_size,
                              hipStream_t stream) {
    const float* x  = (const float*)d_in[0];  // [4,2048,1024]
    const float* w1 = (const float*)d_in[1];  // [4096,1024]
    const float* cw = (const float*)d_in[2];  // [4096,1,3]
    const float* cb = (const float*)d_in[3];  // [4096]
    const float* w2 = (const float*)d_in[4];  // [1024,4096]
    float* out = (float*)d_out;               // [4,2048,1024]
    char* ws = (char*)d_ws;

    // Workspace layout (16B-aligned)
    double* part  = (double*)(ws + 0);          // 2048 doubles
    float*  sc    = (float*)(ws + 16384);       // {scale_w1, dq_w1, scale_w2, dq_w2}
    float*  dqx   = (float*)(ws + 16640);       // 8192 floats
    float*  dqh   = (float*)(ws + 49408);       // 8192 floats
    int8_t* qw1   = (int8_t*)(ws + 82176);      // 4 MB
    int8_t* qw2   = (int8_t*)(ws + 4276480);    // 4 MB
    int8_t* qx    = (int8_t*)(ws + 8470784);    // 8 MB
    int8_t* qh    = (int8_t*)(ws + 16859392);   // 32 MB
    _Float16* h   = (_Float16*)(ws + 50413824); // 64 MB (fp16 now)

    absmean_partial<<<2048, 256, 0, stream>>>((const float4*)w1, (const float4*)w2, part);
    finalize_scales<<<1, 256, 0, stream>>>(part, sc);
    quant_all<<<16384, 256, 0, stream>>>((const float4*)w1, (const float4*)w2,
                                         (const float4*)x, (char4*)qw1, (char4*)qw2,
                                         (char4*)qx, dqx, sc);

    // GEMM1: M=8192, N=4096, K=1024 -> h (fp16)
    dim3 g1(DH / 128, NTOK / 128);
    gemm_i8_pc<_Float16><<<g1, 320, 0, stream>>>(qx, qw1, h, dqx, sc, 1, DH, DM);

    conv_silu_quant<<<NTOK / CT, 512, 0, stream>>>((const half8*)h, (const float4*)cw,
                                                   (const float4*)cb, (char8v*)qh, dqh);

    // GEMM2: M=8192, N=1024, K=4096 -> out (fp32)
    dim3 g2(DM / 128, NTOK / 128);
    gemm_i8_pc<float><<<g2, 320, 0, stream>>>(qh, qw2, out, dqh, sc, 3, DM, DH);
}